// Round 8
// baseline (596.773 us; speedup 1.0000x reference)
//
#include <hip/hip_runtime.h>
#include <math.h>

// Problem constants
#define BATCH   2
#define LSEQ    1024
#define DMODEL  1024
#define DSTATE  16
#define DCONV   4
#define DINNER  2048
#define NROWS   (BATCH * LSEQ)   // 2048

#define LCHUNK  32
#define NCHUNK  32

typedef short  bf16x8 __attribute__((ext_vector_type(8)));
typedef float  f32x4  __attribute__((ext_vector_type(4)));

__device__ __forceinline__ unsigned short f2bf(float f) {
  unsigned int u = __builtin_bit_cast(unsigned int, f);
  u = (u + 0x7fffu + ((u >> 16) & 1u)) >> 16;   // RNE
  return (unsigned short)u;
}
__device__ __forceinline__ float bf2f(unsigned short h) {
  return __builtin_bit_cast(float, (unsigned int)h << 16);
}

// Real XCD id (m09-verified on gfx950). Wave-uniform SGPR read.
__device__ __forceinline__ int get_xcc() {
  int x;
  asm volatile("s_getreg_b32 %0, hwreg(HW_REG_XCC_ID)" : "=s"(x));
  return x & 7;
}

// ---------------------------------------------------------------------------
// Fused input conversion + queue-counter zeroing. 4 regions as in R7.
// ---------------------------------------------------------------------------
__device__ __forceinline__ void cvt_ew_body(const float* __restrict__ s,
                                            unsigned short* __restrict__ d,
                                            int blk, int tid) {
  int i = blk * 256 + tid;
  float4 v = ((const float4*)s)[i];
  ushort4 o;
  o.x = f2bf(v.x); o.y = f2bf(v.y); o.z = f2bf(v.z); o.w = f2bf(v.w);
  ((ushort4*)d)[i] = o;
}

__device__ __forceinline__ void cvt_tr_body(const float* __restrict__ s,
                                            unsigned short* __restrict__ d,
                                            int R, int C, int c0, int r0,
                                            int tid, float (*T)[33]) {
#pragma unroll
  for (int i = 0; i < 4; ++i) {
    int e = tid + i * 256;
    int r = e >> 5, c = e & 31;
    T[r][c] = s[(size_t)(r0 + r) * C + c0 + c];
  }
  __syncthreads();
#pragma unroll
  for (int i = 0; i < 4; ++i) {
    int e = tid + i * 256;
    int c = e >> 5, r = e & 31;
    d[(size_t)(c0 + c) * R + r0 + r] = f2bf(T[r][c]);
  }
}

__global__ __launch_bounds__(256) void cvt_all(
    const float* __restrict__ x, const float* __restrict__ w_in,
    const float* __restrict__ dt_w, const float* __restrict__ out_w,
    unsigned short* __restrict__ XB, unsigned short* __restrict__ WINB,
    unsigned short* __restrict__ DTWB, unsigned short* __restrict__ OWB,
    int* __restrict__ CTRS) {
  __shared__ float T[32][33];
  const int bid = blockIdx.x;
  const int tid = threadIdx.x;
  if (bid == 0 && tid < 24) CTRS[tid] = 0;   // 3 GEMMs x 8 XCD queues
  if (bid < 2048) {
    cvt_ew_body(x, XB, bid, tid);
  } else if (bid < 6144) {
    int t = bid - 2048;
    cvt_tr_body(w_in, WINB, 1024, 4096, (t & 127) * 32, (t >> 7) * 32, tid, T);
  } else if (bid < 10240) {
    cvt_ew_body(dt_w, DTWB, bid - 6144, tid);
  } else {
    int t = bid - 10240;
    cvt_tr_body(out_w, OWB, 2048, 1024, (t & 31) * 32, (t >> 5) * 32, tid, T);
  }
}

// ---------------------------------------------------------------------------
// Queued bf16 MFMA GEMM (NT), XCD-local work assignment.
// Tile 128(M) x 64(N), BK=64, 4 waves each 64x32 (4x2 MFMAs of 16x16x32),
// LDS 24 KB -> 4 blocks/CU at 1024-block launch.
// Job queues: ctr[q] for XCD q. XCD q owns M-panels {2q, 2q+1}; job j in
// queue q decodes ks = j & ((1<<kshift)-1); t = j >> kshift;
// mp = 2q + (t&1); col = t>>1. A-panels (1 MB) stay L2-resident per XCD,
// B streams once -> per-XCD L3 traffic ~9 MB instead of ~48 MB.
// Blocks read their REAL XCD via s_getreg(HW_REG_XCC_ID) and drain their own
// queue first, then steal from the other 7 (guarantees completion regardless
// of placement or XCC_ID semantics - each job runs exactly once).
// Epilogue modes: 0 = fp32 C1 (+ks*zstride)   [out_proj split-K partials]
//                 1 = bf16: col<N1 -> C1 else C2   [in_proj u|res]
//                 2 = softplus(v+bias[col]) -> bf16 C1  [dt_proj]
// ---------------------------------------------------------------------------
__global__ __launch_bounds__(256) void mfma_gemm_q(
    const unsigned short* __restrict__ A, int lda,
    const unsigned short* __restrict__ Bt, int ldb,
    void* __restrict__ C1v, int ld1,
    void* __restrict__ C2v, int ld2, int N1,
    const float* __restrict__ bias,
    int* __restrict__ ctr, int Jper, int kshift,
    int KS, size_t zstride, int mode) {
  __shared__ unsigned short As[8 * 128 * 8];  // 16 KB [kc][row][8]
  __shared__ unsigned short Bs[8 * 64 * 8];   //  8 KB
  __shared__ int sJob;
  const int tid  = threadIdx.x;
  const int wave = tid >> 6;
  const int lane = tid & 63;
  const int wm0 = (wave >> 1) * 64;
  const int wn0 = (wave & 1) * 32;
  const int lkc = lane >> 4, li = lane & 15;
  const int lq = lane >> 4;
  const int x0 = get_xcc();

  for (int qi = 0; qi < 8; ++qi) {
    const int q = (x0 + qi) & 7;
    for (;;) {
      if (tid == 0) sJob = atomicAdd(&ctr[q], 1);
      __syncthreads();
      const int j = sJob;
      __syncthreads();          // all read sJob before tid0's next write
      if (j >= Jper) break;
      // decode job
      const int ks  = j & ((1 << kshift) - 1);
      const int t   = j >> kshift;
      const int row0 = (q * 2 + (t & 1)) * 128;
      const int col0 = (t >> 1) * 64;
      const int kb = ks * KS;

      f32x4 acc[4][2];
#pragma unroll
      for (int i = 0; i < 4; ++i)
#pragma unroll
        for (int jj = 0; jj < 2; ++jj) acc[i][jj] = (f32x4){0.f, 0.f, 0.f, 0.f};

      for (int k0 = kb; k0 < kb + KS; k0 += 64) {
#pragma unroll
        for (int it = 0; it < 4; ++it) {
          int s = it * 256 + tid;        // 0..1023 A slots (16B each)
          int kc = s >> 7, r = s & 127;
          __builtin_amdgcn_global_load_lds(
              (const __attribute__((address_space(1))) void*)(A + (size_t)(row0 + r) * lda + k0 + kc * 8),
              (__attribute__((address_space(3))) void*)(&As[s * 8]), 16, 0, 0);
        }
#pragma unroll
        for (int it = 0; it < 2; ++it) {
          int s = it * 256 + tid;        // 0..511 B slots
          int kc = s >> 6, r = s & 63;
          __builtin_amdgcn_global_load_lds(
              (const __attribute__((address_space(1))) void*)(Bt + (size_t)(col0 + r) * ldb + k0 + kc * 8),
              (__attribute__((address_space(3))) void*)(&Bs[s * 8]), 16, 0, 0);
        }
        __syncthreads();
#pragma unroll
        for (int half = 0; half < 2; ++half) {
          bf16x8 af[4], bfr[2];
#pragma unroll
          for (int mt = 0; mt < 4; ++mt)
            af[mt] = *(const bf16x8*)&As[((half * 4 + lkc) * 128 + wm0 + mt * 16 + li) * 8];
#pragma unroll
          for (int nt = 0; nt < 2; ++nt)
            bfr[nt] = *(const bf16x8*)&Bs[((half * 4 + lkc) * 64 + wn0 + nt * 16 + li) * 8];
#pragma unroll
          for (int mt = 0; mt < 4; ++mt)
#pragma unroll
            for (int nt = 0; nt < 2; ++nt)
              acc[mt][nt] = __builtin_amdgcn_mfma_f32_16x16x32_bf16(
                  af[mt], bfr[nt], acc[mt][nt], 0, 0, 0);
        }
        __syncthreads();
      }
      // Epilogue. C/D layout: col=lane&15, row=(lane>>4)*4+reg (m89-verified)
      const size_t zoff = (size_t)ks * zstride;
#pragma unroll
      for (int mt = 0; mt < 4; ++mt) {
        int gm0 = row0 + wm0 + mt * 16 + lq * 4;
#pragma unroll
        for (int nt = 0; nt < 2; ++nt) {
          int gn = col0 + wn0 + nt * 16 + li;
          if (mode == 0) {
            float* C1 = (float*)C1v;
#pragma unroll
            for (int r = 0; r < 4; ++r)
              C1[zoff + (size_t)(gm0 + r) * ld1 + gn] = acc[mt][nt][r];
          } else if (mode == 1) {
            if (gn < N1) {
              unsigned short* C1 = (unsigned short*)C1v;
#pragma unroll
              for (int r = 0; r < 4; ++r)
                C1[(size_t)(gm0 + r) * ld1 + gn] = f2bf(acc[mt][nt][r]);
            } else {
              unsigned short* C2 = (unsigned short*)C2v;
#pragma unroll
              for (int r = 0; r < 4; ++r)
                C2[(size_t)(gm0 + r) * ld2 + gn - N1] = f2bf(acc[mt][nt][r]);
            }
          } else {  // softplus(v + bias[col]) -> bf16
            unsigned short* C1 = (unsigned short*)C1v;
            float bb = bias[gn];
#pragma unroll
            for (int r = 0; r < 4; ++r) {
              float v = acc[mt][nt][r] + bb;
              v = (v > 20.f) ? v : __logf(1.f + __expf(v));
              C1[(size_t)(gm0 + r) * ld1 + gn] = f2bf(v);
            }
          }
        }
      }
      __syncthreads();   // protect sJob/LDS reuse across jobs
    }
  }
}

// ---------------------------------------------------------------------------
// Split-K reduce for out_proj: out[i] = P0[i] + P1[i], float4.
// ---------------------------------------------------------------------------
__global__ __launch_bounds__(256) void splitk_reduce2(
    const float* __restrict__ P, float* __restrict__ out, int n4, size_t zstride) {
  int i = blockIdx.x * 256 + threadIdx.x;
  if (i >= n4) return;
  float4 a = ((const float4*)P)[i];
  float4 b = ((const float4*)(P + zstride))[i];
  ((float4*)out)[i] = make_float4(a.x + b.x, a.y + b.y, a.z + b.z, a.w + b.w);
}

// ---------------------------------------------------------------------------
// Depthwise causal conv (width 4) + bias + SiLU. bf16 in, bf16 out.
// ---------------------------------------------------------------------------
__global__ __launch_bounds__(256) void conv_silu(
    const unsigned short* __restrict__ UPREB, const float* __restrict__ cw,
    const float* __restrict__ cb, unsigned short* __restrict__ UB) {
  int idx = blockIdx.x * 256 + threadIdx.x;
  int d = idx & (DINNER - 1);
  int l = (idx >> 11) & (LSEQ - 1);
  int b = idx >> 21;
  float acc = cb[d];
#pragma unroll
  for (int k = 0; k < DCONV; ++k) {
    int ll = l + k - (DCONV - 1);
    if (ll >= 0)
      acc += bf2f(UPREB[((size_t)(b * LSEQ + ll)) * DINNER + d]) * cw[d * DCONV + k];
  }
  UB[idx] = f2bf(acc / (1.f + __expf(-acc)));
}

// ---------------------------------------------------------------------------
// x_proj split-K: partial C[64 rows][32 cols] over K-slice of 256.
// ---------------------------------------------------------------------------
__global__ __launch_bounds__(256) void xproj_partial(
    const unsigned short* __restrict__ UB, const float* __restrict__ W,
    float* __restrict__ XPART) {
  const int ks = blockIdx.x;
  const int row0 = blockIdx.y * 64;
  const int kbase = ks * 256;
  __shared__ float Av[16][68];
  __shared__ float Bv[16][32];
  const int tid = threadIdx.x;
  const int col = tid & 31, rg = tid >> 5;
  float acc[8] = {};
  for (int kk = 0; kk < 256; kk += 16) {
#pragma unroll
    for (int i = 0; i < 4; ++i) {
      int e = tid + i * 256;
      int r = e >> 4, k = e & 15;
      Av[k][r] = bf2f(UB[(size_t)(row0 + r) * DINNER + kbase + kk + k]);
    }
#pragma unroll
    for (int i = 0; i < 2; ++i) {
      int e = tid + i * 256;
      int k = e >> 5, c = e & 31;
      Bv[k][c] = W[(size_t)(kbase + kk + k) * 32 + c];
    }
    __syncthreads();
#pragma unroll
    for (int k = 0; k < 16; ++k) {
      float b = Bv[k][col];
#pragma unroll
      for (int r = 0; r < 8; ++r) acc[r] += Av[k][rg * 8 + r] * b;
    }
    __syncthreads();
  }
#pragma unroll
  for (int r = 0; r < 8; ++r)
    XPART[(size_t)ks * NROWS * 32 + (size_t)(row0 + rg * 8 + r) * 32 + col] = acc[r];
}

__global__ __launch_bounds__(256) void xproj_reduce(
    const float* __restrict__ XPART, float* __restrict__ BC) {
  int i = blockIdx.x * 256 + threadIdx.x;
  float s = 0.f;
#pragma unroll
  for (int ks = 0; ks < 8; ++ks) s += XPART[(size_t)ks * NROWS * 32 + i];
  BC[i] = s;
}

// ---------------------------------------------------------------------------
// Scan pass 1: DELTAB holds softplus'd delta (bf16). Per-chunk decay product
// P[n], local state h[n] (h0=0) -> PBUF/HBUF [b][c][n][d].
// ---------------------------------------------------------------------------
__global__ __launch_bounds__(256) void scan_pass1(
    const unsigned short* __restrict__ DELTAB, const unsigned short* __restrict__ UB,
    const float* __restrict__ BC, const float* __restrict__ A_log,
    float* __restrict__ PBUF, float* __restrict__ HBUF) {
  const int bx = blockIdx.x;
  const int b = bx >> 8;
  const int c = (bx >> 3) & (NCHUNK - 1);
  const int d = ((bx & 7) << 8) + threadIdx.x;
  const int l0 = c * LCHUNK;
  __shared__ float sB[LCHUNK * DSTATE];
#pragma unroll
  for (int i = 0; i < 2; ++i) {
    int e = threadIdx.x + i * 256;
    sB[e] = BC[((size_t)(b * LSEQ + l0 + (e >> 4))) * 32 + (e & 15)];
  }
  float Avv[DSTATE];
#pragma unroll
  for (int n = 0; n < DSTATE; ++n) Avv[n] = -__expf(A_log[d * DSTATE + n]);
  float h[DSTATE], P[DSTATE];
#pragma unroll
  for (int n = 0; n < DSTATE; ++n) { h[n] = 0.f; P[n] = 1.f; }
  __syncthreads();
  for (int lc = 0; lc < LCHUNK; ++lc) {
    size_t off = ((size_t)(b * LSEQ + l0 + lc)) * DINNER + d;
    float delta = bf2f(DELTAB[off]);
    float du = delta * bf2f(UB[off]);
#pragma unroll
    for (int n = 0; n < DSTATE; ++n) {
      float dA = __expf(delta * Avv[n]);
      P[n] *= dA;
      h[n] = dA * h[n] + du * sB[lc * DSTATE + n];
    }
  }
  size_t base = ((size_t)(b * NCHUNK + c)) * DSTATE * DINNER + d;
#pragma unroll
  for (int n = 0; n < DSTATE; ++n) {
    PBUF[base + (size_t)n * DINNER] = P[n];
    HBUF[base + (size_t)n * DINNER] = h[n];
  }
}

// ---------------------------------------------------------------------------
// Scan combine: sequential prefix across 32 chunks per (b,n,d); rewrites
// HBUF[c] with the INCOMING state for chunk c.
// ---------------------------------------------------------------------------
__global__ __launch_bounds__(256) void scan_combine(
    const float* __restrict__ PBUF, float* __restrict__ HBUF) {
  const int bx = blockIdx.x;
  const int b = bx >> 7;
  const int n = (bx >> 3) & (DSTATE - 1);
  const int d = ((bx & 7) << 8) + threadIdx.x;
  float h = 0.f;
  for (int c = 0; c < NCHUNK; ++c) {
    size_t idx = (((size_t)(b * NCHUNK + c)) * DSTATE + n) * DINNER + d;
    float p = PBUF[idx];
    float hl = HBUF[idx];
    HBUF[idx] = h;
    h = p * h + hl;
  }
}

// ---------------------------------------------------------------------------
// Scan pass 2: rescan from incoming state; y = C.h + u*D, gate silu(res),
// emit bf16 Y.
// ---------------------------------------------------------------------------
__global__ __launch_bounds__(256) void scan_pass2(
    const unsigned short* __restrict__ DELTAB, const unsigned short* __restrict__ UB,
    const float* __restrict__ BC, const float* __restrict__ HBUF,
    const float* __restrict__ A_log, const float* __restrict__ D_param,
    const unsigned short* __restrict__ RESB, unsigned short* __restrict__ YB) {
  const int bx = blockIdx.x;
  const int b = bx >> 8;
  const int c = (bx >> 3) & (NCHUNK - 1);
  const int d = ((bx & 7) << 8) + threadIdx.x;
  const int l0 = c * LCHUNK;
  __shared__ float sBC[LCHUNK * 32];
#pragma unroll
  for (int i = 0; i < 4; ++i) {
    int e = threadIdx.x + i * 256;
    sBC[e] = BC[((size_t)(b * LSEQ + l0 + (e >> 5))) * 32 + (e & 31)];
  }
  float Avv[DSTATE];
#pragma unroll
  for (int n = 0; n < DSTATE; ++n) Avv[n] = -__expf(A_log[d * DSTATE + n]);
  const float Dp = D_param[d];
  float h[DSTATE];
  size_t base = ((size_t)(b * NCHUNK + c)) * DSTATE * DINNER + d;
#pragma unroll
  for (int n = 0; n < DSTATE; ++n) h[n] = HBUF[base + (size_t)n * DINNER];
  __syncthreads();
  for (int lc = 0; lc < LCHUNK; ++lc) {
    size_t off = ((size_t)(b * LSEQ + l0 + lc)) * DINNER + d;
    float delta = bf2f(DELTAB[off]);
    float uu = bf2f(UB[off]);
    float du = delta * uu;
    float y = 0.f;
#pragma unroll
    for (int n = 0; n < DSTATE; ++n) {
      float dA = __expf(delta * Avv[n]);
      h[n] = dA * h[n] + du * sBC[lc * 32 + n];
      y += h[n] * sBC[lc * 32 + 16 + n];
    }
    y += uu * Dp;
    float r = bf2f(RESB[off]);
    YB[off] = f2bf(y * (r / (1.f + __expf(-r))));
  }
}

// ---------------------------------------------------------------------------
extern "C" void kernel_launch(void* const* d_in, const int* in_sizes, int n_in,
                              void* d_out, int out_size, void* d_ws, size_t ws_size,
                              hipStream_t stream) {
  const float* x       = (const float*)d_in[0];
  const float* w_in    = (const float*)d_in[1];
  const float* conv_w  = (const float*)d_in[2];
  const float* conv_b  = (const float*)d_in[3];
  const float* xproj_w = (const float*)d_in[4];
  const float* dt_w    = (const float*)d_in[5];
  const float* dt_b    = (const float*)d_in[6];
  const float* A_log   = (const float*)d_in[7];
  const float* D_par   = (const float*)d_in[8];
  const float* out_w   = (const float*)d_in[9];
  float* out = (float*)d_out;

  char* ws = (char*)d_ws;
  const size_t MB = 1024 * 1024;
  // bf16 activation buffers
  unsigned short* UPREB  = (unsigned short*)(ws + 0 * MB);   // 8 MB (dead after conv)
  unsigned short* RESB   = (unsigned short*)(ws + 8 * MB);   // 8 MB (dead after pass2)
  unsigned short* UB     = (unsigned short*)(ws + 16 * MB);  // 8 MB
  unsigned short* DELTAB = (unsigned short*)(ws + 24 * MB);  // 8 MB
  unsigned short* YB     = (unsigned short*)(ws + 32 * MB);  // 8 MB
  unsigned short* XB     = (unsigned short*)(ws + 40 * MB);  // 4 MB (dead after in_proj)
  unsigned short* WINB   = (unsigned short*)(ws + 44 * MB);  // 8 MB (dead after in_proj)
  unsigned short* DTWB   = (unsigned short*)(ws + 52 * MB);  // 8 MB (dead after dt_proj)
  unsigned short* OWB    = (unsigned short*)(ws + 60 * MB);  // 4 MB (live to end)
  // overlays (first written strictly after underlying buffer dies)
  float* PBUF  = (float*)(ws + 0 * MB);                 // 8 MB over UPREB (w: pass1)
  float* HBUF  = (float*)(ws + 40 * MB);                // 8 MB over XB+WINB[0:4] (w: pass1)
  float* BCb   = (float*)(ws + 48 * MB);                // 256 KB over WINB[4:]
  float* XPART = (float*)(ws + 48 * MB + 512 * 1024);   // 2 MB over WINB[4:]
  float* OPART = (float*)(ws + 0 * MB);                 // 16 MB over PBUF+RESB (w: out_proj)
  int*   CTRS  = (int*)(ws + 64 * MB);                  // 24 queue counters
  // footprint: 64 MB + 96 B

  dim3 blk(256);
  // input conversions + counter zeroing
  cvt_all<<<dim3(12288), blk, 0, stream>>>(x, w_in, dt_w, out_w, XB, WINB, DTWB, OWB, CTRS);
  // in_proj: XB(2048x1024) x WINB(4096x1024)^T -> UPREB | RESB (bf16)
  // jobs/XCD = 2 m-panels x 64 col-tiles = 128, kshift=0, KS=1024
  mfma_gemm_q<<<dim3(1024), blk, 0, stream>>>(
      XB, DMODEL, WINB, DMODEL, UPREB, DINNER, RESB, DINNER, DINNER,
      nullptr, CTRS + 0, 128, 0, DMODEL, 0, 1);
  // conv + silu -> UB bf16
  conv_silu<<<dim3(NROWS * DINNER / 256), blk, 0, stream>>>(UPREB, conv_w, conv_b, UB);
  // x_proj split-K -> BC
  xproj_partial<<<dim3(8, NROWS / 64), blk, 0, stream>>>(UB, xproj_w, XPART);
  xproj_reduce<<<dim3(NROWS * 32 / 256), blk, 0, stream>>>(XPART, BCb);
  // dt_proj: UB x DTWB^T, softplus(+dt_b) epilogue -> DELTAB bf16
  // jobs/XCD = 2 x 32 = 64, kshift=0, KS=2048
  mfma_gemm_q<<<dim3(1024), blk, 0, stream>>>(
      UB, DINNER, DTWB, DINNER, DELTAB, DINNER, nullptr, 0, DINNER,
      dt_b, CTRS + 8, 64, 0, DINNER, 0, 2);
  // chunked selective scan
  scan_pass1<<<dim3(BATCH * NCHUNK * (DINNER / 256)), blk, 0, stream>>>(
      DELTAB, UB, BCb, A_log, PBUF, HBUF);
  scan_combine<<<dim3(BATCH * DSTATE * (DINNER / 256)), blk, 0, stream>>>(PBUF, HBUF);
  scan_pass2<<<dim3(BATCH * NCHUNK * (DINNER / 256)), blk, 0, stream>>>(
      DELTAB, UB, BCb, HBUF, A_log, D_par, RESB, YB);
  // out_proj: YB(2048x2048) x OWB(1024x2048)^T, split-K=2 via job dim
  // jobs/XCD = 2 m x 16 col x 2 kslices = 64, kshift=1, KS=1024
  const size_t ZS = (size_t)NROWS * DMODEL;
  mfma_gemm_q<<<dim3(1024), blk, 0, stream>>>(
      YB, DINNER, OWB, DINNER, OPART, DMODEL, nullptr, 0, DMODEL,
      nullptr, CTRS + 16, 64, 1, DINNER / 2, ZS, 0);
  splitk_reduce2<<<dim3(NROWS * DMODEL / 1024), blk, 0, stream>>>(
      OPART, out, NROWS * DMODEL / 4, ZS);
}

// Round 9
// 336.018 us; speedup vs baseline: 1.7760x; 1.7760x over previous
//
#include <hip/hip_runtime.h>
#include <math.h>

// Problem constants
#define BATCH   2
#define LSEQ    1024
#define DMODEL  1024
#define DSTATE  16
#define DCONV   4
#define DINNER  2048
#define NROWS   (BATCH * LSEQ)   // 2048

#define LCHUNK  32
#define NCHUNK  32

typedef short  bf16x8 __attribute__((ext_vector_type(8)));
typedef float  f32x4  __attribute__((ext_vector_type(4)));

__device__ __forceinline__ unsigned short f2bf(float f) {
  unsigned int u = __builtin_bit_cast(unsigned int, f);
  u = (u + 0x7fffu + ((u >> 16) & 1u)) >> 16;   // RNE
  return (unsigned short)u;
}
__device__ __forceinline__ float bf2f(unsigned short h) {
  return __builtin_bit_cast(float, (unsigned int)h << 16);
}

// ---------------------------------------------------------------------------
// Fused input conversion (R7-proven). 4 regions.
// ---------------------------------------------------------------------------
__device__ __forceinline__ void cvt_ew_body(const float* __restrict__ s,
                                            unsigned short* __restrict__ d,
                                            int blk, int tid) {
  int i = blk * 256 + tid;
  float4 v = ((const float4*)s)[i];
  ushort4 o;
  o.x = f2bf(v.x); o.y = f2bf(v.y); o.z = f2bf(v.z); o.w = f2bf(v.w);
  ((ushort4*)d)[i] = o;
}

__device__ __forceinline__ void cvt_tr_body(const float* __restrict__ s,
                                            unsigned short* __restrict__ d,
                                            int R, int C, int c0, int r0,
                                            int tid, float (*T)[33]) {
#pragma unroll
  for (int i = 0; i < 4; ++i) {
    int e = tid + i * 256;
    int r = e >> 5, c = e & 31;
    T[r][c] = s[(size_t)(r0 + r) * C + c0 + c];
  }
  __syncthreads();
#pragma unroll
  for (int i = 0; i < 4; ++i) {
    int e = tid + i * 256;
    int c = e >> 5, r = e & 31;
    d[(size_t)(c0 + c) * R + r0 + r] = f2bf(T[r][c]);
  }
}

__global__ __launch_bounds__(256) void cvt_all(
    const float* __restrict__ x, const float* __restrict__ w_in,
    const float* __restrict__ dt_w, const float* __restrict__ out_w,
    unsigned short* __restrict__ XB, unsigned short* __restrict__ WINB,
    unsigned short* __restrict__ DTWB, unsigned short* __restrict__ OWB) {
  __shared__ float T[32][33];
  const int bid = blockIdx.x;
  const int tid = threadIdx.x;
  if (bid < 2048) {
    cvt_ew_body(x, XB, bid, tid);
  } else if (bid < 6144) {
    int t = bid - 2048;
    cvt_tr_body(w_in, WINB, 1024, 4096, (t & 127) * 32, (t >> 7) * 32, tid, T);
  } else if (bid < 10240) {
    cvt_ew_body(dt_w, DTWB, bid - 6144, tid);
  } else {
    int t = bid - 10240;
    cvt_tr_body(out_w, OWB, 2048, 1024, (t & 31) * 32, (t >> 5) * 32, tid, T);
  }
}

// ---------------------------------------------------------------------------
// bf16 MFMA GEMM (NT) — the R5-measured-best config, restored:
// 128(M) x 64(N) tile, 4 waves each 64x32 (4x2 MFMAs of 16x16x32), BK=64,
// single-buffer 2-barrier K-loop, LDS 24 KB (4+ blocks/CU at >=1024 blocks).
// Static XCD swizzle (requires gridDim.y==16): xcd=linear%8 owns M-panels
// {2x,2x+1}. R8's dynamic queue version regressed 2.5x — keep this static.
// Split-K via gridDim.z, out += z*zstride (mode 0 fp32 partials).
// Epilogue modes: 0 = fp32 C1 (+zoff)            [out_proj partials]
//                 1 = bf16 col<N1 -> C1 else C2  [in_proj u|res]
//                 2 = softplus(v+bias[col]) bf16 [dt_proj]
// ---------------------------------------------------------------------------
__global__ __launch_bounds__(256) void mfma_gemm_nt(
    const unsigned short* __restrict__ A, int lda,
    const unsigned short* __restrict__ Bt, int ldb,
    void* __restrict__ C1v, int ld1,
    void* __restrict__ C2v, int ld2, int N1,
    const float* __restrict__ bias,
    int KS, size_t zstride, int mode) {
  __shared__ unsigned short As[8 * 128 * 8];  // 16 KB [kc][row][8]
  __shared__ unsigned short Bs[8 * 64 * 8];   //  8 KB
  const int tid  = threadIdx.x;
  const int wave = tid >> 6;
  const int lane = tid & 63;
  const int linear = blockIdx.y * gridDim.x + blockIdx.x;
  const int xcd = linear & 7;
  const int pos = linear >> 3;
  const int row0 = (xcd * 2 + (pos & 1)) * 128;   // 16 M-panels
  const int col0 = (pos >> 1) * 64;
  const int wm0 = (wave >> 1) * 64;
  const int wn0 = (wave & 1) * 32;
  const int kb = blockIdx.z * KS;

  f32x4 acc[4][2];
#pragma unroll
  for (int i = 0; i < 4; ++i)
#pragma unroll
    for (int j = 0; j < 2; ++j) acc[i][j] = (f32x4){0.f, 0.f, 0.f, 0.f};

  const int lkc = lane >> 4, li = lane & 15;
  for (int k0 = kb; k0 < kb + KS; k0 += 64) {
#pragma unroll
    for (int it = 0; it < 4; ++it) {
      int s = it * 256 + tid;        // 0..1023 A slots (16B each)
      int kc = s >> 7, r = s & 127;
      __builtin_amdgcn_global_load_lds(
          (const __attribute__((address_space(1))) void*)(A + (size_t)(row0 + r) * lda + k0 + kc * 8),
          (__attribute__((address_space(3))) void*)(&As[s * 8]), 16, 0, 0);
    }
#pragma unroll
    for (int it = 0; it < 2; ++it) {
      int s = it * 256 + tid;        // 0..511 B slots
      int kc = s >> 6, r = s & 63;
      __builtin_amdgcn_global_load_lds(
          (const __attribute__((address_space(1))) void*)(Bt + (size_t)(col0 + r) * ldb + k0 + kc * 8),
          (__attribute__((address_space(3))) void*)(&Bs[s * 8]), 16, 0, 0);
    }
    __syncthreads();
#pragma unroll
    for (int half = 0; half < 2; ++half) {
      bf16x8 af[4], bfr[2];
#pragma unroll
      for (int mt = 0; mt < 4; ++mt)
        af[mt] = *(const bf16x8*)&As[((half * 4 + lkc) * 128 + wm0 + mt * 16 + li) * 8];
#pragma unroll
      for (int nt = 0; nt < 2; ++nt)
        bfr[nt] = *(const bf16x8*)&Bs[((half * 4 + lkc) * 64 + wn0 + nt * 16 + li) * 8];
#pragma unroll
      for (int mt = 0; mt < 4; ++mt)
#pragma unroll
        for (int nt = 0; nt < 2; ++nt)
          acc[mt][nt] = __builtin_amdgcn_mfma_f32_16x16x32_bf16(
              af[mt], bfr[nt], acc[mt][nt], 0, 0, 0);
    }
    __syncthreads();
  }
  // C/D layout: col=lane&15, row=(lane>>4)*4+reg (m89-verified)
  const int lq = lane >> 4;
  const size_t zoff = (size_t)blockIdx.z * zstride;
#pragma unroll
  for (int mt = 0; mt < 4; ++mt) {
    int gm0 = row0 + wm0 + mt * 16 + lq * 4;
#pragma unroll
    for (int nt = 0; nt < 2; ++nt) {
      int gn = col0 + wn0 + nt * 16 + li;
      if (mode == 0) {
        float* C1 = (float*)C1v;
#pragma unroll
        for (int r = 0; r < 4; ++r)
          C1[zoff + (size_t)(gm0 + r) * ld1 + gn] = acc[mt][nt][r];
      } else if (mode == 1) {
        if (gn < N1) {
          unsigned short* C1 = (unsigned short*)C1v;
#pragma unroll
          for (int r = 0; r < 4; ++r)
            C1[(size_t)(gm0 + r) * ld1 + gn] = f2bf(acc[mt][nt][r]);
        } else {
          unsigned short* C2 = (unsigned short*)C2v;
#pragma unroll
          for (int r = 0; r < 4; ++r)
            C2[(size_t)(gm0 + r) * ld2 + gn - N1] = f2bf(acc[mt][nt][r]);
        }
      } else {  // mode 2: softplus(v + bias[col]) -> bf16
        unsigned short* C1 = (unsigned short*)C1v;
        float bb = bias[gn];
#pragma unroll
        for (int r = 0; r < 4; ++r) {
          float v = acc[mt][nt][r] + bb;
          v = (v > 20.f) ? v : __logf(1.f + __expf(v));
          C1[(size_t)(gm0 + r) * ld1 + gn] = f2bf(v);
        }
      }
    }
  }
}

// ---------------------------------------------------------------------------
// Split-K reduce for out_proj: out[i] = P0[i] + P1[i], float4.
// ---------------------------------------------------------------------------
__global__ __launch_bounds__(256) void splitk_reduce2(
    const float* __restrict__ P, float* __restrict__ out, int n4, size_t zstride) {
  int i = blockIdx.x * 256 + threadIdx.x;
  if (i >= n4) return;
  float4 a = ((const float4*)P)[i];
  float4 b = ((const float4*)(P + zstride))[i];
  ((float4*)out)[i] = make_float4(a.x + b.x, a.y + b.y, a.z + b.z, a.w + b.w);
}

// ---------------------------------------------------------------------------
// Depthwise causal conv (width 4) + bias + SiLU. bf16 in, bf16 out.
// ---------------------------------------------------------------------------
__global__ __launch_bounds__(256) void conv_silu(
    const unsigned short* __restrict__ UPREB, const float* __restrict__ cw,
    const float* __restrict__ cb, unsigned short* __restrict__ UB) {
  int idx = blockIdx.x * 256 + threadIdx.x;
  int d = idx & (DINNER - 1);
  int l = (idx >> 11) & (LSEQ - 1);
  int b = idx >> 21;
  float acc = cb[d];
#pragma unroll
  for (int k = 0; k < DCONV; ++k) {
    int ll = l + k - (DCONV - 1);
    if (ll >= 0)
      acc += bf2f(UPREB[((size_t)(b * LSEQ + ll)) * DINNER + d]) * cw[d * DCONV + k];
  }
  UB[idx] = f2bf(acc / (1.f + __expf(-acc)));
}

// ---------------------------------------------------------------------------
// x_proj split-K: partial C[64 rows][32 cols] over K-slice of 256.
// ---------------------------------------------------------------------------
__global__ __launch_bounds__(256) void xproj_partial(
    const unsigned short* __restrict__ UB, const float* __restrict__ W,
    float* __restrict__ XPART) {
  const int ks = blockIdx.x;
  const int row0 = blockIdx.y * 64;
  const int kbase = ks * 256;
  __shared__ float Av[16][68];
  __shared__ float Bv[16][32];
  const int tid = threadIdx.x;
  const int col = tid & 31, rg = tid >> 5;
  float acc[8] = {};
  for (int kk = 0; kk < 256; kk += 16) {
#pragma unroll
    for (int i = 0; i < 4; ++i) {
      int e = tid + i * 256;
      int r = e >> 4, k = e & 15;
      Av[k][r] = bf2f(UB[(size_t)(row0 + r) * DINNER + kbase + kk + k]);
    }
#pragma unroll
    for (int i = 0; i < 2; ++i) {
      int e = tid + i * 256;
      int k = e >> 5, c = e & 31;
      Bv[k][c] = W[(size_t)(kbase + kk + k) * 32 + c];
    }
    __syncthreads();
#pragma unroll
    for (int k = 0; k < 16; ++k) {
      float b = Bv[k][col];
#pragma unroll
      for (int r = 0; r < 8; ++r) acc[r] += Av[k][rg * 8 + r] * b;
    }
    __syncthreads();
  }
#pragma unroll
  for (int r = 0; r < 8; ++r)
    XPART[(size_t)ks * NROWS * 32 + (size_t)(row0 + rg * 8 + r) * 32 + col] = acc[r];
}

__global__ __launch_bounds__(256) void xproj_reduce(
    const float* __restrict__ XPART, float* __restrict__ BC) {
  int i = blockIdx.x * 256 + threadIdx.x;
  float s = 0.f;
#pragma unroll
  for (int ks = 0; ks < 8; ++ks) s += XPART[(size_t)ks * NROWS * 32 + i];
  BC[i] = s;
}

// ---------------------------------------------------------------------------
// Scan pass 1: per-chunk decay product P[n], local state h[n] (h0=0).
// ---------------------------------------------------------------------------
__global__ __launch_bounds__(256) void scan_pass1(
    const unsigned short* __restrict__ DELTAB, const unsigned short* __restrict__ UB,
    const float* __restrict__ BC, const float* __restrict__ A_log,
    float* __restrict__ PBUF, float* __restrict__ HBUF) {
  const int bx = blockIdx.x;
  const int b = bx >> 8;
  const int c = (bx >> 3) & (NCHUNK - 1);
  const int d = ((bx & 7) << 8) + threadIdx.x;
  const int l0 = c * LCHUNK;
  __shared__ float sB[LCHUNK * DSTATE];
#pragma unroll
  for (int i = 0; i < 2; ++i) {
    int e = threadIdx.x + i * 256;
    sB[e] = BC[((size_t)(b * LSEQ + l0 + (e >> 4))) * 32 + (e & 15)];
  }
  float Avv[DSTATE];
#pragma unroll
  for (int n = 0; n < DSTATE; ++n) Avv[n] = -__expf(A_log[d * DSTATE + n]);
  float h[DSTATE], P[DSTATE];
#pragma unroll
  for (int n = 0; n < DSTATE; ++n) { h[n] = 0.f; P[n] = 1.f; }
  __syncthreads();
  for (int lc = 0; lc < LCHUNK; ++lc) {
    size_t off = ((size_t)(b * LSEQ + l0 + lc)) * DINNER + d;
    float delta = bf2f(DELTAB[off]);
    float du = delta * bf2f(UB[off]);
#pragma unroll
    for (int n = 0; n < DSTATE; ++n) {
      float dA = __expf(delta * Avv[n]);
      P[n] *= dA;
      h[n] = dA * h[n] + du * sB[lc * DSTATE + n];
    }
  }
  size_t base = ((size_t)(b * NCHUNK + c)) * DSTATE * DINNER + d;
#pragma unroll
  for (int n = 0; n < DSTATE; ++n) {
    PBUF[base + (size_t)n * DINNER] = P[n];
    HBUF[base + (size_t)n * DINNER] = h[n];
  }
}

// ---------------------------------------------------------------------------
// Scan combine: sequential prefix across 32 chunks per (b,n,d).
// ---------------------------------------------------------------------------
__global__ __launch_bounds__(256) void scan_combine(
    const float* __restrict__ PBUF, float* __restrict__ HBUF) {
  const int bx = blockIdx.x;
  const int b = bx >> 7;
  const int n = (bx >> 3) & (DSTATE - 1);
  const int d = ((bx & 7) << 8) + threadIdx.x;
  float h = 0.f;
  for (int c = 0; c < NCHUNK; ++c) {
    size_t idx = (((size_t)(b * NCHUNK + c)) * DSTATE + n) * DINNER + d;
    float p = PBUF[idx];
    float hl = HBUF[idx];
    HBUF[idx] = h;
    h = p * h + hl;
  }
}

// ---------------------------------------------------------------------------
// Scan pass 2: rescan from incoming state; y = C.h + u*D, gate silu(res),
// emit bf16 Y.
// ---------------------------------------------------------------------------
__global__ __launch_bounds__(256) void scan_pass2(
    const unsigned short* __restrict__ DELTAB, const unsigned short* __restrict__ UB,
    const float* __restrict__ BC, const float* __restrict__ HBUF,
    const float* __restrict__ A_log, const float* __restrict__ D_param,
    const unsigned short* __restrict__ RESB, unsigned short* __restrict__ YB) {
  const int bx = blockIdx.x;
  const int b = bx >> 8;
  const int c = (bx >> 3) & (NCHUNK - 1);
  const int d = ((bx & 7) << 8) + threadIdx.x;
  const int l0 = c * LCHUNK;
  __shared__ float sBC[LCHUNK * 32];
#pragma unroll
  for (int i = 0; i < 4; ++i) {
    int e = threadIdx.x + i * 256;
    sBC[e] = BC[((size_t)(b * LSEQ + l0 + (e >> 5))) * 32 + (e & 31)];
  }
  float Avv[DSTATE];
#pragma unroll
  for (int n = 0; n < DSTATE; ++n) Avv[n] = -__expf(A_log[d * DSTATE + n]);
  const float Dp = D_param[d];
  float h[DSTATE];
  size_t base = ((size_t)(b * NCHUNK + c)) * DSTATE * DINNER + d;
#pragma unroll
  for (int n = 0; n < DSTATE; ++n) h[n] = HBUF[base + (size_t)n * DINNER];
  __syncthreads();
  for (int lc = 0; lc < LCHUNK; ++lc) {
    size_t off = ((size_t)(b * LSEQ + l0 + lc)) * DINNER + d;
    float delta = bf2f(DELTAB[off]);
    float uu = bf2f(UB[off]);
    float du = delta * uu;
    float y = 0.f;
#pragma unroll
    for (int n = 0; n < DSTATE; ++n) {
      float dA = __expf(delta * Avv[n]);
      h[n] = dA * h[n] + du * sBC[lc * 32 + n];
      y += h[n] * sBC[lc * 32 + 16 + n];
    }
    y += uu * Dp;
    float r = bf2f(RESB[off]);
    YB[off] = f2bf(y * (r / (1.f + __expf(-r))));
  }
}

// ---------------------------------------------------------------------------
extern "C" void kernel_launch(void* const* d_in, const int* in_sizes, int n_in,
                              void* d_out, int out_size, void* d_ws, size_t ws_size,
                              hipStream_t stream) {
  const float* x       = (const float*)d_in[0];
  const float* w_in    = (const float*)d_in[1];
  const float* conv_w  = (const float*)d_in[2];
  const float* conv_b  = (const float*)d_in[3];
  const float* xproj_w = (const float*)d_in[4];
  const float* dt_w    = (const float*)d_in[5];
  const float* dt_b    = (const float*)d_in[6];
  const float* A_log   = (const float*)d_in[7];
  const float* D_par   = (const float*)d_in[8];
  const float* out_w   = (const float*)d_in[9];
  float* out = (float*)d_out;

  char* ws = (char*)d_ws;
  const size_t MB = 1024 * 1024;
  // bf16 activation buffers
  unsigned short* UPREB  = (unsigned short*)(ws + 0 * MB);   // 8 MB (dead after conv)
  unsigned short* RESB   = (unsigned short*)(ws + 8 * MB);   // 8 MB (dead after pass2)
  unsigned short* UB     = (unsigned short*)(ws + 16 * MB);  // 8 MB
  unsigned short* DELTAB = (unsigned short*)(ws + 24 * MB);  // 8 MB
  unsigned short* YB     = (unsigned short*)(ws + 32 * MB);  // 8 MB
  unsigned short* XB     = (unsigned short*)(ws + 40 * MB);  // 4 MB (dead after in_proj)
  unsigned short* WINB   = (unsigned short*)(ws + 44 * MB);  // 8 MB (dead after in_proj)
  unsigned short* DTWB   = (unsigned short*)(ws + 52 * MB);  // 8 MB (dead after dt_proj)
  unsigned short* OWB    = (unsigned short*)(ws + 60 * MB);  // 4 MB (live to end)
  // overlays (first written strictly after underlying buffer dies)
  float* PBUF  = (float*)(ws + 0 * MB);                 // 8 MB over UPREB (w: pass1)
  float* HBUF  = (float*)(ws + 40 * MB);                // 8 MB over XB+WINB[0:4] (w: pass1)
  float* BCb   = (float*)(ws + 48 * MB);                // 256 KB over WINB[4:]
  float* XPART = (float*)(ws + 48 * MB + 512 * 1024);   // 2 MB over WINB[4:]
  float* OPART = (float*)(ws + 0 * MB);                 // 16 MB over PBUF+RESB (w: out_proj)
  // footprint: 64 MB

  dim3 blk(256);
  // input conversions
  cvt_all<<<dim3(12288), blk, 0, stream>>>(x, w_in, dt_w, out_w, XB, WINB, DTWB, OWB);
  // in_proj: XB(2048x1024) x WINB(4096x1024)^T -> UPREB | RESB bf16  (1024 blocks)
  mfma_gemm_nt<<<dim3(2 * DINNER / 64, NROWS / 128, 1), blk, 0, stream>>>(
      XB, DMODEL, WINB, DMODEL, UPREB, DINNER, RESB, DINNER, DINNER,
      nullptr, DMODEL, 0, 1);
  // conv + silu -> UB bf16
  conv_silu<<<dim3(NROWS * DINNER / 256), blk, 0, stream>>>(UPREB, conv_w, conv_b, UB);
  // x_proj split-K -> BC
  xproj_partial<<<dim3(8, NROWS / 64), blk, 0, stream>>>(UB, xproj_w, XPART);
  xproj_reduce<<<dim3(NROWS * 32 / 256), blk, 0, stream>>>(XPART, BCb);
  // dt_proj: UB x DTWB^T, softplus(+dt_b) epilogue -> DELTAB bf16  (512 blocks)
  mfma_gemm_nt<<<dim3(DINNER / 64, NROWS / 128, 1), blk, 0, stream>>>(
      UB, DINNER, DTWB, DINNER, DELTAB, DINNER, nullptr, 0, DINNER,
      dt_b, DINNER, 0, 2);
  // chunked selective scan
  scan_pass1<<<dim3(BATCH * NCHUNK * (DINNER / 256)), blk, 0, stream>>>(
      DELTAB, UB, BCb, A_log, PBUF, HBUF);
  scan_combine<<<dim3(BATCH * DSTATE * (DINNER / 256)), blk, 0, stream>>>(PBUF, HBUF);
  scan_pass2<<<dim3(BATCH * NCHUNK * (DINNER / 256)), blk, 0, stream>>>(
      DELTAB, UB, BCb, HBUF, A_log, D_par, RESB, YB);
  // out_proj: YB(2048x2048) x OWB(1024x2048)^T, split-K=2 -> OPART fp32 (512 blocks)
  const size_t ZS = (size_t)NROWS * DMODEL;
  mfma_gemm_nt<<<dim3(DMODEL / 64, NROWS / 128, 2), blk, 0, stream>>>(
      YB, DINNER, OWB, DINNER, OPART, DMODEL, nullptr, 0, DMODEL,
      nullptr, DINNER / 2, ZS, 0);
  splitk_reduce2<<<dim3(NROWS * DMODEL / 1024), blk, 0, stream>>>(
      OPART, out, NROWS * DMODEL / 4, ZS);
}

// Round 10
// 329.971 us; speedup vs baseline: 1.8086x; 1.0183x over previous
//
#include <hip/hip_runtime.h>
#include <math.h>

// Problem constants
#define BATCH   2
#define LSEQ    1024
#define DMODEL  1024
#define DSTATE  16
#define DCONV   4
#define DINNER  2048
#define NROWS   (BATCH * LSEQ)   // 2048

#define LCHUNK  32
#define NCHUNK  32

typedef short  bf16x8 __attribute__((ext_vector_type(8)));
typedef float  f32x4  __attribute__((ext_vector_type(4)));

__device__ __forceinline__ unsigned short f2bf(float f) {
  unsigned int u = __builtin_bit_cast(unsigned int, f);
  u = (u + 0x7fffu + ((u >> 16) & 1u)) >> 16;   // RNE
  return (unsigned short)u;
}
__device__ __forceinline__ float bf2f(unsigned short h) {
  return __builtin_bit_cast(float, (unsigned int)h << 16);
}

// ---------------------------------------------------------------------------
// Fused input conversion (R7-proven). 4 regions.
// ---------------------------------------------------------------------------
__device__ __forceinline__ void cvt_ew_body(const float* __restrict__ s,
                                            unsigned short* __restrict__ d,
                                            int blk, int tid) {
  int i = blk * 256 + tid;
  float4 v = ((const float4*)s)[i];
  ushort4 o;
  o.x = f2bf(v.x); o.y = f2bf(v.y); o.z = f2bf(v.z); o.w = f2bf(v.w);
  ((ushort4*)d)[i] = o;
}

__device__ __forceinline__ void cvt_tr_body(const float* __restrict__ s,
                                            unsigned short* __restrict__ d,
                                            int R, int C, int c0, int r0,
                                            int tid, float (*T)[33]) {
#pragma unroll
  for (int i = 0; i < 4; ++i) {
    int e = tid + i * 256;
    int r = e >> 5, c = e & 31;
    T[r][c] = s[(size_t)(r0 + r) * C + c0 + c];
  }
  __syncthreads();
#pragma unroll
  for (int i = 0; i < 4; ++i) {
    int e = tid + i * 256;
    int c = e >> 5, r = e & 31;
    d[(size_t)(c0 + c) * R + r0 + r] = f2bf(T[r][c]);
  }
}

__global__ __launch_bounds__(256) void cvt_all(
    const float* __restrict__ x, const float* __restrict__ w_in,
    const float* __restrict__ dt_w, const float* __restrict__ out_w,
    unsigned short* __restrict__ XB, unsigned short* __restrict__ WINB,
    unsigned short* __restrict__ DTWB, unsigned short* __restrict__ OWB) {
  __shared__ float T[32][33];
  const int bid = blockIdx.x;
  const int tid = threadIdx.x;
  if (bid < 2048) {
    cvt_ew_body(x, XB, bid, tid);
  } else if (bid < 6144) {
    int t = bid - 2048;
    cvt_tr_body(w_in, WINB, 1024, 4096, (t & 127) * 32, (t >> 7) * 32, tid, T);
  } else if (bid < 10240) {
    cvt_ew_body(dt_w, DTWB, bid - 6144, tid);
  } else {
    int t = bid - 10240;
    cvt_tr_body(out_w, OWB, 2048, 1024, (t & 31) * 32, (t >> 5) * 32, tid, T);
  }
}

// ---------------------------------------------------------------------------
// bf16 MFMA GEMM (NT), 512-thread / BN=128 variant.
// Rationale (R9 post-mortem): per-CU vmem service saturates ~10 B/cyc; only
// bytes and waves/CU matter. BM=128 x BN=128 cuts staging traffic 33% vs
// BN=64 (K*(1/128+1/128) B/elem), and 512 threads = 8 waves/block keeps
// 8-16 waves/CU WITHOUT split-K partials (R7's BN=128 failed at 4 waves/CU).
// 8 waves: wave w -> rows (w>>2)*64, cols (w&3)*32; each wave 4x2 MFMAs of
// 16x16x32. BK=64, LDS 2x16 KB, single-buffer 2-barrier loop (proven best).
// Static XCD swizzle (gridDim.y==16): xcd=linear%8 owns M-panels {2x,2x+1}.
// Split-K via gridDim.z, out += z*zstride (mode 0 fp32 partials).
// Epilogue modes: 0 = fp32 C1 (+zoff)            [out_proj partials]
//                 1 = bf16 col<N1 -> C1 else C2  [in_proj u|res]
//                 2 = softplus(v+bias[col]) bf16 [dt_proj]
// ---------------------------------------------------------------------------
__global__ __launch_bounds__(512) void mfma_gemm_nt(
    const unsigned short* __restrict__ A, int lda,
    const unsigned short* __restrict__ Bt, int ldb,
    void* __restrict__ C1v, int ld1,
    void* __restrict__ C2v, int ld2, int N1,
    const float* __restrict__ bias,
    int KS, size_t zstride, int mode) {
  __shared__ unsigned short As[8 * 128 * 8];  // 16 KB [kc][row][8]
  __shared__ unsigned short Bs[8 * 128 * 8];  // 16 KB
  const int tid  = threadIdx.x;
  const int wave = tid >> 6;        // 0..7
  const int lane = tid & 63;
  const int linear = blockIdx.y * gridDim.x + blockIdx.x;
  const int xcd = linear & 7;
  const int pos = linear >> 3;
  const int row0 = (xcd * 2 + (pos & 1)) * 128;   // 16 M-panels
  const int col0 = (pos >> 1) * 128;
  const int wm0 = (wave >> 2) * 64;
  const int wn0 = (wave & 3) * 32;
  const int kb = blockIdx.z * KS;

  f32x4 acc[4][2];
#pragma unroll
  for (int i = 0; i < 4; ++i)
#pragma unroll
    for (int j = 0; j < 2; ++j) acc[i][j] = (f32x4){0.f, 0.f, 0.f, 0.f};

  const int lkc = lane >> 4, li = lane & 15;
  for (int k0 = kb; k0 < kb + KS; k0 += 64) {
#pragma unroll
    for (int it = 0; it < 2; ++it) {
      int s = it * 512 + tid;        // 0..1023 A slots (16B each)
      int kc = s >> 7, r = s & 127;
      __builtin_amdgcn_global_load_lds(
          (const __attribute__((address_space(1))) void*)(A + (size_t)(row0 + r) * lda + k0 + kc * 8),
          (__attribute__((address_space(3))) void*)(&As[s * 8]), 16, 0, 0);
    }
#pragma unroll
    for (int it = 0; it < 2; ++it) {
      int s = it * 512 + tid;        // 0..1023 B slots
      int kc = s >> 7, r = s & 127;
      __builtin_amdgcn_global_load_lds(
          (const __attribute__((address_space(1))) void*)(Bt + (size_t)(col0 + r) * ldb + k0 + kc * 8),
          (__attribute__((address_space(3))) void*)(&Bs[s * 8]), 16, 0, 0);
    }
    __syncthreads();
#pragma unroll
    for (int half = 0; half < 2; ++half) {
      bf16x8 af[4], bfr[2];
#pragma unroll
      for (int mt = 0; mt < 4; ++mt)
        af[mt] = *(const bf16x8*)&As[((half * 4 + lkc) * 128 + wm0 + mt * 16 + li) * 8];
#pragma unroll
      for (int nt = 0; nt < 2; ++nt)
        bfr[nt] = *(const bf16x8*)&Bs[((half * 4 + lkc) * 128 + wn0 + nt * 16 + li) * 8];
#pragma unroll
      for (int mt = 0; mt < 4; ++mt)
#pragma unroll
        for (int nt = 0; nt < 2; ++nt)
          acc[mt][nt] = __builtin_amdgcn_mfma_f32_16x16x32_bf16(
              af[mt], bfr[nt], acc[mt][nt], 0, 0, 0);
    }
    __syncthreads();
  }
  // C/D layout: col=lane&15, row=(lane>>4)*4+reg (m89-verified)
  const int lq = lane >> 4;
  const size_t zoff = (size_t)blockIdx.z * zstride;
#pragma unroll
  for (int mt = 0; mt < 4; ++mt) {
    int gm0 = row0 + wm0 + mt * 16 + lq * 4;
#pragma unroll
    for (int nt = 0; nt < 2; ++nt) {
      int gn = col0 + wn0 + nt * 16 + li;
      if (mode == 0) {
        float* C1 = (float*)C1v;
#pragma unroll
        for (int r = 0; r < 4; ++r)
          C1[zoff + (size_t)(gm0 + r) * ld1 + gn] = acc[mt][nt][r];
      } else if (mode == 1) {
        if (gn < N1) {
          unsigned short* C1 = (unsigned short*)C1v;
#pragma unroll
          for (int r = 0; r < 4; ++r)
            C1[(size_t)(gm0 + r) * ld1 + gn] = f2bf(acc[mt][nt][r]);
        } else {
          unsigned short* C2 = (unsigned short*)C2v;
#pragma unroll
          for (int r = 0; r < 4; ++r)
            C2[(size_t)(gm0 + r) * ld2 + gn - N1] = f2bf(acc[mt][nt][r]);
        }
      } else {  // mode 2: softplus(v + bias[col]) -> bf16
        unsigned short* C1 = (unsigned short*)C1v;
        float bb = bias[gn];
#pragma unroll
        for (int r = 0; r < 4; ++r) {
          float v = acc[mt][nt][r] + bb;
          v = (v > 20.f) ? v : __logf(1.f + __expf(v));
          C1[(size_t)(gm0 + r) * ld1 + gn] = f2bf(v);
        }
      }
    }
  }
}

// ---------------------------------------------------------------------------
// Split-K reduce for out_proj: out[i] = P0[i] + P1[i], float4.
// ---------------------------------------------------------------------------
__global__ __launch_bounds__(256) void splitk_reduce2(
    const float* __restrict__ P, float* __restrict__ out, int n4, size_t zstride) {
  int i = blockIdx.x * 256 + threadIdx.x;
  if (i >= n4) return;
  float4 a = ((const float4*)P)[i];
  float4 b = ((const float4*)(P + zstride))[i];
  ((float4*)out)[i] = make_float4(a.x + b.x, a.y + b.y, a.z + b.z, a.w + b.w);
}

// ---------------------------------------------------------------------------
// Depthwise causal conv (width 4) + bias + SiLU. bf16 in, bf16 out.
// ---------------------------------------------------------------------------
__global__ __launch_bounds__(256) void conv_silu(
    const unsigned short* __restrict__ UPREB, const float* __restrict__ cw,
    const float* __restrict__ cb, unsigned short* __restrict__ UB) {
  int idx = blockIdx.x * 256 + threadIdx.x;
  int d = idx & (DINNER - 1);
  int l = (idx >> 11) & (LSEQ - 1);
  int b = idx >> 21;
  float acc = cb[d];
#pragma unroll
  for (int k = 0; k < DCONV; ++k) {
    int ll = l + k - (DCONV - 1);
    if (ll >= 0)
      acc += bf2f(UPREB[((size_t)(b * LSEQ + ll)) * DINNER + d]) * cw[d * DCONV + k];
  }
  UB[idx] = f2bf(acc / (1.f + __expf(-acc)));
}

// ---------------------------------------------------------------------------
// x_proj split-K: partial C[64 rows][32 cols] over K-slice of 256.
// ---------------------------------------------------------------------------
__global__ __launch_bounds__(256) void xproj_partial(
    const unsigned short* __restrict__ UB, const float* __restrict__ W,
    float* __restrict__ XPART) {
  const int ks = blockIdx.x;
  const int row0 = blockIdx.y * 64;
  const int kbase = ks * 256;
  __shared__ float Av[16][68];
  __shared__ float Bv[16][32];
  const int tid = threadIdx.x;
  const int col = tid & 31, rg = tid >> 5;
  float acc[8] = {};
  for (int kk = 0; kk < 256; kk += 16) {
#pragma unroll
    for (int i = 0; i < 4; ++i) {
      int e = tid + i * 256;
      int r = e >> 4, k = e & 15;
      Av[k][r] = bf2f(UB[(size_t)(row0 + r) * DINNER + kbase + kk + k]);
    }
#pragma unroll
    for (int i = 0; i < 2; ++i) {
      int e = tid + i * 256;
      int k = e >> 5, c = e & 31;
      Bv[k][c] = W[(size_t)(kbase + kk + k) * 32 + c];
    }
    __syncthreads();
#pragma unroll
    for (int k = 0; k < 16; ++k) {
      float b = Bv[k][col];
#pragma unroll
      for (int r = 0; r < 8; ++r) acc[r] += Av[k][rg * 8 + r] * b;
    }
    __syncthreads();
  }
#pragma unroll
  for (int r = 0; r < 8; ++r)
    XPART[(size_t)ks * NROWS * 32 + (size_t)(row0 + rg * 8 + r) * 32 + col] = acc[r];
}

__global__ __launch_bounds__(256) void xproj_reduce(
    const float* __restrict__ XPART, float* __restrict__ BC) {
  int i = blockIdx.x * 256 + threadIdx.x;
  float s = 0.f;
#pragma unroll
  for (int ks = 0; ks < 8; ++ks) s += XPART[(size_t)ks * NROWS * 32 + i];
  BC[i] = s;
}

// ---------------------------------------------------------------------------
// Scan pass 1: per-chunk decay product P[n], local state h[n] (h0=0).
// ---------------------------------------------------------------------------
__global__ __launch_bounds__(256) void scan_pass1(
    const unsigned short* __restrict__ DELTAB, const unsigned short* __restrict__ UB,
    const float* __restrict__ BC, const float* __restrict__ A_log,
    float* __restrict__ PBUF, float* __restrict__ HBUF) {
  const int bx = blockIdx.x;
  const int b = bx >> 8;
  const int c = (bx >> 3) & (NCHUNK - 1);
  const int d = ((bx & 7) << 8) + threadIdx.x;
  const int l0 = c * LCHUNK;
  __shared__ float sB[LCHUNK * DSTATE];
#pragma unroll
  for (int i = 0; i < 2; ++i) {
    int e = threadIdx.x + i * 256;
    sB[e] = BC[((size_t)(b * LSEQ + l0 + (e >> 4))) * 32 + (e & 15)];
  }
  float Avv[DSTATE];
#pragma unroll
  for (int n = 0; n < DSTATE; ++n) Avv[n] = -__expf(A_log[d * DSTATE + n]);
  float h[DSTATE], P[DSTATE];
#pragma unroll
  for (int n = 0; n < DSTATE; ++n) { h[n] = 0.f; P[n] = 1.f; }
  __syncthreads();
  for (int lc = 0; lc < LCHUNK; ++lc) {
    size_t off = ((size_t)(b * LSEQ + l0 + lc)) * DINNER + d;
    float delta = bf2f(DELTAB[off]);
    float du = delta * bf2f(UB[off]);
#pragma unroll
    for (int n = 0; n < DSTATE; ++n) {
      float dA = __expf(delta * Avv[n]);
      P[n] *= dA;
      h[n] = dA * h[n] + du * sB[lc * DSTATE + n];
    }
  }
  size_t base = ((size_t)(b * NCHUNK + c)) * DSTATE * DINNER + d;
#pragma unroll
  for (int n = 0; n < DSTATE; ++n) {
    PBUF[base + (size_t)n * DINNER] = P[n];
    HBUF[base + (size_t)n * DINNER] = h[n];
  }
}

// ---------------------------------------------------------------------------
// Scan combine: sequential prefix across 32 chunks per (b,n,d).
// ---------------------------------------------------------------------------
__global__ __launch_bounds__(256) void scan_combine(
    const float* __restrict__ PBUF, float* __restrict__ HBUF) {
  const int bx = blockIdx.x;
  const int b = bx >> 7;
  const int n = (bx >> 3) & (DSTATE - 1);
  const int d = ((bx & 7) << 8) + threadIdx.x;
  float h = 0.f;
  for (int c = 0; c < NCHUNK; ++c) {
    size_t idx = (((size_t)(b * NCHUNK + c)) * DSTATE + n) * DINNER + d;
    float p = PBUF[idx];
    float hl = HBUF[idx];
    HBUF[idx] = h;
    h = p * h + hl;
  }
}

// ---------------------------------------------------------------------------
// Scan pass 2: rescan from incoming state; y = C.h + u*D, gate silu(res),
// emit bf16 Y.
// ---------------------------------------------------------------------------
__global__ __launch_bounds__(256) void scan_pass2(
    const unsigned short* __restrict__ DELTAB, const unsigned short* __restrict__ UB,
    const float* __restrict__ BC, const float* __restrict__ HBUF,
    const float* __restrict__ A_log, const float* __restrict__ D_param,
    const unsigned short* __restrict__ RESB, unsigned short* __restrict__ YB) {
  const int bx = blockIdx.x;
  const int b = bx >> 8;
  const int c = (bx >> 3) & (NCHUNK - 1);
  const int d = ((bx & 7) << 8) + threadIdx.x;
  const int l0 = c * LCHUNK;
  __shared__ float sBC[LCHUNK * 32];
#pragma unroll
  for (int i = 0; i < 4; ++i) {
    int e = threadIdx.x + i * 256;
    sBC[e] = BC[((size_t)(b * LSEQ + l0 + (e >> 5))) * 32 + (e & 31)];
  }
  float Avv[DSTATE];
#pragma unroll
  for (int n = 0; n < DSTATE; ++n) Avv[n] = -__expf(A_log[d * DSTATE + n]);
  const float Dp = D_param[d];
  float h[DSTATE];
  size_t base = ((size_t)(b * NCHUNK + c)) * DSTATE * DINNER + d;
#pragma unroll
  for (int n = 0; n < DSTATE; ++n) h[n] = HBUF[base + (size_t)n * DINNER];
  __syncthreads();
  for (int lc = 0; lc < LCHUNK; ++lc) {
    size_t off = ((size_t)(b * LSEQ + l0 + lc)) * DINNER + d;
    float delta = bf2f(DELTAB[off]);
    float uu = bf2f(UB[off]);
    float du = delta * uu;
    float y = 0.f;
#pragma unroll
    for (int n = 0; n < DSTATE; ++n) {
      float dA = __expf(delta * Avv[n]);
      h[n] = dA * h[n] + du * sBC[lc * 32 + n];
      y += h[n] * sBC[lc * 32 + 16 + n];
    }
    y += uu * Dp;
    float r = bf2f(RESB[off]);
    YB[off] = f2bf(y * (r / (1.f + __expf(-r))));
  }
}

// ---------------------------------------------------------------------------
extern "C" void kernel_launch(void* const* d_in, const int* in_sizes, int n_in,
                              void* d_out, int out_size, void* d_ws, size_t ws_size,
                              hipStream_t stream) {
  const float* x       = (const float*)d_in[0];
  const float* w_in    = (const float*)d_in[1];
  const float* conv_w  = (const float*)d_in[2];
  const float* conv_b  = (const float*)d_in[3];
  const float* xproj_w = (const float*)d_in[4];
  const float* dt_w    = (const float*)d_in[5];
  const float* dt_b    = (const float*)d_in[6];
  const float* A_log   = (const float*)d_in[7];
  const float* D_par   = (const float*)d_in[8];
  const float* out_w   = (const float*)d_in[9];
  float* out = (float*)d_out;

  char* ws = (char*)d_ws;
  const size_t MB = 1024 * 1024;
  // bf16 activation buffers
  unsigned short* UPREB  = (unsigned short*)(ws + 0 * MB);   // 8 MB (dead after conv)
  unsigned short* RESB   = (unsigned short*)(ws + 8 * MB);   // 8 MB (dead after pass2)
  unsigned short* UB     = (unsigned short*)(ws + 16 * MB);  // 8 MB
  unsigned short* DELTAB = (unsigned short*)(ws + 24 * MB);  // 8 MB
  unsigned short* YB     = (unsigned short*)(ws + 32 * MB);  // 8 MB
  unsigned short* XB     = (unsigned short*)(ws + 40 * MB);  // 4 MB (dead after in_proj)
  unsigned short* WINB   = (unsigned short*)(ws + 44 * MB);  // 8 MB (dead after in_proj)
  unsigned short* DTWB   = (unsigned short*)(ws + 52 * MB);  // 8 MB (dead after dt_proj)
  unsigned short* OWB    = (unsigned short*)(ws + 60 * MB);  // 4 MB (live to end)
  // overlays (first written strictly after underlying buffer dies)
  float* PBUF  = (float*)(ws + 0 * MB);                 // 8 MB over UPREB (w: pass1)
  float* HBUF  = (float*)(ws + 40 * MB);                // 8 MB over XB+WINB[0:4] (w: pass1)
  float* BCb   = (float*)(ws + 48 * MB);                // 256 KB over WINB[4:]
  float* XPART = (float*)(ws + 48 * MB + 512 * 1024);   // 2 MB over WINB[4:]
  float* OPART = (float*)(ws + 0 * MB);                 // 16 MB over PBUF+RESB (w: out_proj)
  // footprint: 64 MB

  // input conversions
  cvt_all<<<dim3(12288), dim3(256), 0, stream>>>(x, w_in, dt_w, out_w, XB, WINB, DTWB, OWB);
  // in_proj: XB(2048x1024) x WINB(4096x1024)^T -> UPREB | RESB bf16
  // grid 32x16 = 512 blocks x 512 thr = 16 waves/CU, 268 MB staging
  mfma_gemm_nt<<<dim3(2 * DINNER / 128, NROWS / 128, 1), dim3(512), 0, stream>>>(
      XB, DMODEL, WINB, DMODEL, UPREB, DINNER, RESB, DINNER, DINNER,
      nullptr, DMODEL, 0, 1);
  // conv + silu -> UB bf16
  conv_silu<<<dim3(NROWS * DINNER / 256), dim3(256), 0, stream>>>(UPREB, conv_w, conv_b, UB);
  // x_proj split-K -> BC
  xproj_partial<<<dim3(8, NROWS / 64), dim3(256), 0, stream>>>(UB, xproj_w, XPART);
  xproj_reduce<<<dim3(NROWS * 32 / 256), dim3(256), 0, stream>>>(XPART, BCb);
  // dt_proj: UB x DTWB^T, softplus(+dt_b) epilogue -> DELTAB bf16
  // grid 16x16 = 256 blocks x 512 thr = 8 waves/CU, 268 MB staging
  mfma_gemm_nt<<<dim3(DINNER / 128, NROWS / 128, 1), dim3(512), 0, stream>>>(
      UB, DINNER, DTWB, DINNER, DELTAB, DINNER, nullptr, 0, DINNER,
      dt_b, DINNER, 0, 2);
  // chunked selective scan
  scan_pass1<<<dim3(BATCH * NCHUNK * (DINNER / 256)), dim3(256), 0, stream>>>(
      DELTAB, UB, BCb, A_log, PBUF, HBUF);
  scan_combine<<<dim3(BATCH * DSTATE * (DINNER / 256)), dim3(256), 0, stream>>>(PBUF, HBUF);
  scan_pass2<<<dim3(BATCH * NCHUNK * (DINNER / 256)), dim3(256), 0, stream>>>(
      DELTAB, UB, BCb, HBUF, A_log, D_par, RESB, YB);
  // out_proj: YB(2048x2048) x OWB(1024x2048)^T, split-K=2 -> OPART fp32
  // grid 8x16x2 = 256 blocks x 512 thr = 8 waves/CU
  const size_t ZS = (size_t)NROWS * DMODEL;
  mfma_gemm_nt<<<dim3(DMODEL / 128, NROWS / 128, 2), dim3(512), 0, stream>>>(
      YB, DINNER, OWB, DINNER, OPART, DMODEL, nullptr, 0, DMODEL,
      nullptr, DINNER / 2, ZS, 0);
  splitk_reduce2<<<dim3(NROWS * DMODEL / 1024), dim3(256), 0, stream>>>(
      OPART, out, NROWS * DMODEL / 4, ZS);
}